// Round 1
// baseline (814.782 us; speedup 1.0000x reference)
//
#include <hip/hip_runtime.h>

#define DIN 256
#define DOUT 64

// ---------------- degree kernel ----------------
__global__ __launch_bounds__(256) void degree_kernel(
    const int* __restrict__ src, const int* __restrict__ dst,
    float* __restrict__ outdeg, float* __restrict__ indeg, int n_edges)
{
    int i = blockIdx.x * blockDim.x + threadIdx.x;
    if (i < n_edges) {
        unsafeAtomicAdd(&outdeg[src[i]], 1.0f);
        unsafeAtomicAdd(&indeg[dst[i]], 1.0f);
    }
}

// ---------------- GEMM: h = (x * norm_src) @ W ----------------
// 64 rows x 64 cols per block, 256 threads, 4x4 micro-tile, BK=64.
__global__ __launch_bounds__(256) void gemm_norm_kernel(
    const float* __restrict__ x, const float* __restrict__ W,
    const float* __restrict__ outdeg, float* __restrict__ h, int n_nodes)
{
    __shared__ float xs[64][68];  // row stride 68 floats = 272B (16B-aligned, breaks bank pow2)
    __shared__ float wt[64][68];

    const int tid = threadIdx.x;
    const int ty = tid >> 4;    // 0..15
    const int tx = tid & 15;    // 0..15
    const int r0 = blockIdx.x * 64;

    float acc[4][4] = {};

    for (int k0 = 0; k0 < DIN; k0 += 64) {
        // load x tile: 64 rows x 64 k  (each thread: 4 float4)
        #pragma unroll
        for (int i = 0; i < 4; ++i) {
            int row = (tid >> 4) + 16 * i;       // 0..63
            int c4  = tid & 15;                  // 0..15
            int grow = r0 + row;
            float4 v = make_float4(0.f, 0.f, 0.f, 0.f);
            if (grow < n_nodes)
                v = *reinterpret_cast<const float4*>(&x[(size_t)grow * DIN + k0 + c4 * 4]);
            *reinterpret_cast<float4*>(&xs[row][c4 * 4]) = v;
        }
        // load W tile: 64 k x 64 cols
        #pragma unroll
        for (int i = 0; i < 4; ++i) {
            int krow = (tid >> 4) + 16 * i;      // 0..63
            int c4   = tid & 15;
            float4 v = *reinterpret_cast<const float4*>(&W[(size_t)(k0 + krow) * DOUT + c4 * 4]);
            *reinterpret_cast<float4*>(&wt[krow][c4 * 4]) = v;
        }
        __syncthreads();

        #pragma unroll
        for (int k = 0; k < 64; ++k) {
            float a[4], b[4];
            #pragma unroll
            for (int i = 0; i < 4; ++i) a[i] = xs[ty * 4 + i][k];
            #pragma unroll
            for (int j = 0; j < 4; ++j) b[j] = wt[k][tx * 4 + j];
            #pragma unroll
            for (int i = 0; i < 4; ++i)
                #pragma unroll
                for (int j = 0; j < 4; ++j)
                    acc[i][j] = fmaf(a[i], b[j], acc[i][j]);
        }
        __syncthreads();
    }

    // apply norm_src per row, store h
    #pragma unroll
    for (int i = 0; i < 4; ++i) {
        int grow = r0 + ty * 4 + i;
        if (grow >= n_nodes) continue;
        float ns = rsqrtf(fmaxf(outdeg[grow], 1.0f));
        float4 v = make_float4(acc[i][0] * ns, acc[i][1] * ns, acc[i][2] * ns, acc[i][3] * ns);
        *reinterpret_cast<float4*>(&h[(size_t)grow * DOUT + tx * 4]) = v;
    }
}

// ---------------- scatter: agg[dst] += h[src] ----------------
// One thread per (edge, 4-col chunk): 16 threads/edge.
__global__ __launch_bounds__(256) void scatter_kernel(
    const float* __restrict__ h, const int* __restrict__ src,
    const int* __restrict__ dst, float* __restrict__ agg, int n_edges)
{
    int idx = blockIdx.x * blockDim.x + threadIdx.x;
    if (idx >= n_edges * 16) return;
    int e = idx >> 4;
    int q = idx & 15;
    int s = src[e];
    int d = dst[e];
    float4 v = *reinterpret_cast<const float4*>(&h[(size_t)s * DOUT + q * 4]);
    float* o = &agg[(size_t)d * DOUT + q * 4];
    unsafeAtomicAdd(&o[0], v.x);
    unsafeAtomicAdd(&o[1], v.y);
    unsafeAtomicAdd(&o[2], v.z);
    unsafeAtomicAdd(&o[3], v.w);
}

// ---------------- epilogue: out = relu(agg * norm_dst + b), in place ----------------
__global__ __launch_bounds__(256) void finalize_kernel(
    float* __restrict__ out, const float* __restrict__ indeg,
    const float* __restrict__ b, int n_nodes)
{
    int idx = blockIdx.x * blockDim.x + threadIdx.x;
    if (idx >= n_nodes * 16) return;
    int n = idx >> 4;
    int q = idx & 15;
    float nd = rsqrtf(fmaxf(indeg[n], 1.0f));
    float4 v  = *reinterpret_cast<float4*>(&out[(size_t)n * DOUT + q * 4]);
    float4 bb = *reinterpret_cast<const float4*>(&b[q * 4]);
    v.x = fmaxf(fmaf(v.x, nd, bb.x), 0.f);
    v.y = fmaxf(fmaf(v.y, nd, bb.y), 0.f);
    v.z = fmaxf(fmaf(v.z, nd, bb.z), 0.f);
    v.w = fmaxf(fmaf(v.w, nd, bb.w), 0.f);
    *reinterpret_cast<float4*>(&out[(size_t)n * DOUT + q * 4]) = v;
}

extern "C" void kernel_launch(void* const* d_in, const int* in_sizes, int n_in,
                              void* d_out, int out_size, void* d_ws, size_t ws_size,
                              hipStream_t stream) {
    const float* x   = (const float*)d_in[0];
    const float* W   = (const float*)d_in[1];
    const float* b   = (const float*)d_in[2];
    const int*   src = (const int*)d_in[3];
    const int*   dst = (const int*)d_in[4];
    float* out = (float*)d_out;

    const int n_nodes = in_sizes[0] / DIN;   // 50000
    const int n_edges = in_sizes[3];         // 800000

    // workspace layout: [outdeg n][indeg n][h n*64]
    float* outdeg = (float*)d_ws;
    float* indeg  = outdeg + n_nodes;
    float* h      = indeg + n_nodes;

    // zero degrees and the output accumulator (d_out doubles as agg buffer)
    hipMemsetAsync(outdeg, 0, (size_t)2 * n_nodes * sizeof(float), stream);
    hipMemsetAsync(out, 0, (size_t)n_nodes * DOUT * sizeof(float), stream);

    degree_kernel<<<(n_edges + 255) / 256, 256, 0, stream>>>(src, dst, outdeg, indeg, n_edges);
    gemm_norm_kernel<<<(n_nodes + 63) / 64, 256, 0, stream>>>(x, W, outdeg, h, n_nodes);
    scatter_kernel<<<((size_t)n_edges * 16 + 255) / 256, 256, 0, stream>>>(h, src, dst, out, n_edges);
    finalize_kernel<<<((size_t)n_nodes * 16 + 255) / 256, 256, 0, stream>>>(out, indeg, b, n_nodes);
}

// Round 2
// 319.062 us; speedup vs baseline: 2.5537x; 2.5537x over previous
//
#include <hip/hip_runtime.h>

#define DIN 256
#define DOUT 64

// ---------------- degree kernel (int counts) ----------------
__global__ __launch_bounds__(256) void degree_kernel(
    const int* __restrict__ src, const int* __restrict__ dst,
    int* __restrict__ outdeg, int* __restrict__ indeg, int n_edges)
{
    int i = blockIdx.x * blockDim.x + threadIdx.x;
    if (i < n_edges) {
        atomicAdd(&outdeg[src[i]], 1);
        atomicAdd(&indeg[dst[i]], 1);
    }
}

// ---------------- exclusive scan of indeg -> rowptr, cursor (single workgroup) ----------------
__global__ __launch_bounds__(256) void scan_kernel(
    const int* __restrict__ indeg, int* __restrict__ rowptr,
    int* __restrict__ cursor, int n)
{
    __shared__ int sums[256];
    const int t = threadIdx.x;
    const int chunk = (n + 255) / 256;
    const int beg = t * chunk;
    const int end = min(beg + chunk, n);

    int s = 0;
    for (int i = beg; i < end; ++i) s += indeg[i];
    sums[t] = s;
    __syncthreads();

    // Hillis-Steele inclusive scan over 256 partials
    for (int off = 1; off < 256; off <<= 1) {
        int v = 0;
        if (t >= off) v = sums[t - off];
        __syncthreads();
        if (t >= off) sums[t] += v;
        __syncthreads();
    }

    int excl = (t == 0) ? 0 : sums[t - 1];
    for (int i = beg; i < end; ++i) {
        rowptr[i] = excl;
        cursor[i] = excl;
        excl += indeg[i];
    }
    if (t == 255) rowptr[n] = excl;
}

// ---------------- CSR fill: col[pos] = src, bucketed by dst ----------------
__global__ __launch_bounds__(256) void fill_csr_kernel(
    const int* __restrict__ src, const int* __restrict__ dst,
    int* __restrict__ cursor, int* __restrict__ col, int n_edges)
{
    int e = blockIdx.x * blockDim.x + threadIdx.x;
    if (e < n_edges) {
        int pos = atomicAdd(&cursor[dst[e]], 1);
        col[pos] = src[e];
    }
}

// ---------------- GEMM: h = (x * norm_src) @ W ----------------
// 64 rows x 64 cols per block, 256 threads, 4x4 micro-tile, BK=64.
__global__ __launch_bounds__(256) void gemm_norm_kernel(
    const float* __restrict__ x, const float* __restrict__ W,
    const int* __restrict__ outdeg, float* __restrict__ h, int n_nodes)
{
    __shared__ float xs[64][68];
    __shared__ float wt[64][68];

    const int tid = threadIdx.x;
    const int ty = tid >> 4;    // 0..15
    const int tx = tid & 15;    // 0..15
    const int r0 = blockIdx.x * 64;

    float acc[4][4] = {};

    for (int k0 = 0; k0 < DIN; k0 += 64) {
        #pragma unroll
        for (int i = 0; i < 4; ++i) {
            int row = (tid >> 4) + 16 * i;
            int c4  = tid & 15;
            int grow = r0 + row;
            float4 v = make_float4(0.f, 0.f, 0.f, 0.f);
            if (grow < n_nodes)
                v = *reinterpret_cast<const float4*>(&x[(size_t)grow * DIN + k0 + c4 * 4]);
            *reinterpret_cast<float4*>(&xs[row][c4 * 4]) = v;
        }
        #pragma unroll
        for (int i = 0; i < 4; ++i) {
            int krow = (tid >> 4) + 16 * i;
            int c4   = tid & 15;
            float4 v = *reinterpret_cast<const float4*>(&W[(size_t)(k0 + krow) * DOUT + c4 * 4]);
            *reinterpret_cast<float4*>(&wt[krow][c4 * 4]) = v;
        }
        __syncthreads();

        #pragma unroll
        for (int k = 0; k < 64; ++k) {
            float a[4], b[4];
            #pragma unroll
            for (int i = 0; i < 4; ++i) a[i] = xs[ty * 4 + i][k];
            #pragma unroll
            for (int j = 0; j < 4; ++j) b[j] = wt[k][tx * 4 + j];
            #pragma unroll
            for (int i = 0; i < 4; ++i)
                #pragma unroll
                for (int j = 0; j < 4; ++j)
                    acc[i][j] = fmaf(a[i], b[j], acc[i][j]);
        }
        __syncthreads();
    }

    #pragma unroll
    for (int i = 0; i < 4; ++i) {
        int grow = r0 + ty * 4 + i;
        if (grow >= n_nodes) continue;
        float ns = rsqrtf(fmaxf((float)outdeg[grow], 1.0f));
        float4 v = make_float4(acc[i][0] * ns, acc[i][1] * ns, acc[i][2] * ns, acc[i][3] * ns);
        *reinterpret_cast<float4*>(&h[(size_t)grow * DOUT + tx * 4]) = v;
    }
}

// ---------------- gather + finalize: one wave per dst node, lane = column ----------------
__global__ __launch_bounds__(256) void gather_kernel(
    const float* __restrict__ h, const int* __restrict__ rowptr,
    const int* __restrict__ col, const float* __restrict__ bias,
    float* __restrict__ out, int n_nodes)
{
    int wave = (blockIdx.x * blockDim.x + threadIdx.x) >> 6;
    int lane = threadIdx.x & 63;
    if (wave >= n_nodes) return;

    const int beg = rowptr[wave];
    const int end = rowptr[wave + 1];
    const int deg = end - beg;

    float acc = 0.f;
    int i = beg;
    // 4-way unroll for memory-level parallelism
    for (; i + 4 <= end; i += 4) {
        int s0 = col[i], s1 = col[i + 1], s2 = col[i + 2], s3 = col[i + 3];
        float v0 = h[(size_t)s0 * DOUT + lane];
        float v1 = h[(size_t)s1 * DOUT + lane];
        float v2 = h[(size_t)s2 * DOUT + lane];
        float v3 = h[(size_t)s3 * DOUT + lane];
        acc += (v0 + v1) + (v2 + v3);
    }
    for (; i < end; ++i) {
        acc += h[(size_t)col[i] * DOUT + lane];
    }

    float nd = rsqrtf(fmaxf((float)deg, 1.0f));
    out[(size_t)wave * DOUT + lane] = fmaxf(fmaf(acc, nd, bias[lane]), 0.f);
}

extern "C" void kernel_launch(void* const* d_in, const int* in_sizes, int n_in,
                              void* d_out, int out_size, void* d_ws, size_t ws_size,
                              hipStream_t stream) {
    const float* x   = (const float*)d_in[0];
    const float* W   = (const float*)d_in[1];
    const float* b   = (const float*)d_in[2];
    const int*   src = (const int*)d_in[3];
    const int*   dst = (const int*)d_in[4];
    float* out = (float*)d_out;

    const int n_nodes = in_sizes[0] / DIN;   // 50000
    const int n_edges = in_sizes[3];         // 800000

    // workspace layout (ints first, then 16B-aligned float h)
    int* outdeg = (int*)d_ws;                  // n
    int* indeg  = outdeg + n_nodes;            // n
    int* rowptr = indeg + n_nodes;             // n+1
    int* cursor = rowptr + n_nodes + 1;        // n
    int* col    = cursor + n_nodes;            // n_edges
    size_t int_count = (size_t)4 * n_nodes + 1 + n_edges;
    size_t h_off = ((int_count * sizeof(int) + 15) / 16) * 16;
    float* h = (float*)((char*)d_ws + h_off);  // n*64

    // zero the degree accumulators (must be re-zeroed every call)
    hipMemsetAsync(outdeg, 0, (size_t)2 * n_nodes * sizeof(int), stream);

    degree_kernel<<<(n_edges + 255) / 256, 256, 0, stream>>>(src, dst, outdeg, indeg, n_edges);
    scan_kernel<<<1, 256, 0, stream>>>(indeg, rowptr, cursor, n_nodes);
    fill_csr_kernel<<<(n_edges + 255) / 256, 256, 0, stream>>>(src, dst, cursor, col, n_edges);
    gemm_norm_kernel<<<(n_nodes + 63) / 64, 256, 0, stream>>>(x, W, outdeg, h, n_nodes);
    gather_kernel<<<((size_t)n_nodes * 64 + 255) / 256, 256, 0, stream>>>(h, rowptr, col, b, out, n_nodes);
}

// Round 3
// 207.170 us; speedup vs baseline: 3.9329x; 1.5401x over previous
//
#include <hip/hip_runtime.h>

#define DIN 256
#define DOUT 64
#define SCAN_BLK 256

// ---------------- degree kernel (int counts) ----------------
__global__ __launch_bounds__(256) void degree_kernel(
    const int* __restrict__ src, const int* __restrict__ dst,
    int* __restrict__ outdeg, int* __restrict__ indeg, int n_edges)
{
    int i = blockIdx.x * blockDim.x + threadIdx.x;
    if (i < n_edges) {
        atomicAdd(&outdeg[src[i]], 1);
        atomicAdd(&indeg[dst[i]], 1);
    }
}

// ---------------- scan phase 1: per-block sums ----------------
__global__ __launch_bounds__(SCAN_BLK) void partial_kernel(
    const int* __restrict__ indeg, int* __restrict__ bsum, int n)
{
    __shared__ int red[SCAN_BLK / 64];
    int idx = blockIdx.x * SCAN_BLK + threadIdx.x;
    int v = (idx < n) ? indeg[idx] : 0;
    // wave reduce
    #pragma unroll
    for (int off = 32; off >= 1; off >>= 1)
        v += __shfl_down(v, off, 64);
    int wid = threadIdx.x >> 6;
    if ((threadIdx.x & 63) == 0) red[wid] = v;
    __syncthreads();
    if (threadIdx.x == 0) {
        int s = 0;
        #pragma unroll
        for (int w = 0; w < SCAN_BLK / 64; ++w) s += red[w];
        bsum[blockIdx.x] = s;
    }
}

// ---------------- scan phase 2: exclusive scan of block sums (1 block) ----------------
__global__ __launch_bounds__(256) void scan_bsums_kernel(
    int* __restrict__ bsum, int* __restrict__ boff, int nblocks)
{
    __shared__ int s[256];
    int t = threadIdx.x;
    int v = (t < nblocks) ? bsum[t] : 0;
    s[t] = v;
    __syncthreads();
    for (int off = 1; off < 256; off <<= 1) {
        int u = 0;
        if (t >= off) u = s[t - off];
        __syncthreads();
        if (t >= off) s[t] += u;
        __syncthreads();
    }
    if (t < nblocks) boff[t] = s[t] - v;  // exclusive
}

// ---------------- scan phase 3: emit rowptr & cursor ----------------
__global__ __launch_bounds__(SCAN_BLK) void emit_kernel(
    const int* __restrict__ indeg, const int* __restrict__ boff,
    int* __restrict__ rowptr, int* __restrict__ cursor, int n, int n_edges)
{
    __shared__ int s[SCAN_BLK];
    int t = threadIdx.x;
    int idx = blockIdx.x * SCAN_BLK + t;
    int v = (idx < n) ? indeg[idx] : 0;
    s[t] = v;
    __syncthreads();
    for (int off = 1; off < SCAN_BLK; off <<= 1) {
        int u = 0;
        if (t >= off) u = s[t - off];
        __syncthreads();
        if (t >= off) s[t] += u;
        __syncthreads();
    }
    if (idx < n) {
        int excl = boff[blockIdx.x] + s[t] - v;
        rowptr[idx] = excl;
        cursor[idx] = excl;
    }
    if (idx == 0) rowptr[n] = n_edges;  // total is statically known
}

// ---------------- CSR fill: col[pos] = src, bucketed by dst ----------------
__global__ __launch_bounds__(256) void fill_csr_kernel(
    const int* __restrict__ src, const int* __restrict__ dst,
    int* __restrict__ cursor, int* __restrict__ col, int n_edges)
{
    int e = blockIdx.x * blockDim.x + threadIdx.x;
    if (e < n_edges) {
        int pos = atomicAdd(&cursor[dst[e]], 1);
        col[pos] = src[e];
    }
}

// ---------------- GEMM: h = (x * norm_src) @ W ----------------
__global__ __launch_bounds__(256) void gemm_norm_kernel(
    const float* __restrict__ x, const float* __restrict__ W,
    const int* __restrict__ outdeg, float* __restrict__ h, int n_nodes)
{
    __shared__ float xs[64][68];
    __shared__ float wt[64][68];

    const int tid = threadIdx.x;
    const int ty = tid >> 4;    // 0..15
    const int tx = tid & 15;    // 0..15
    const int r0 = blockIdx.x * 64;

    float acc[4][4] = {};

    for (int k0 = 0; k0 < DIN; k0 += 64) {
        #pragma unroll
        for (int i = 0; i < 4; ++i) {
            int row = (tid >> 4) + 16 * i;
            int c4  = tid & 15;
            int grow = r0 + row;
            float4 v = make_float4(0.f, 0.f, 0.f, 0.f);
            if (grow < n_nodes)
                v = *reinterpret_cast<const float4*>(&x[(size_t)grow * DIN + k0 + c4 * 4]);
            *reinterpret_cast<float4*>(&xs[row][c4 * 4]) = v;
        }
        #pragma unroll
        for (int i = 0; i < 4; ++i) {
            int krow = (tid >> 4) + 16 * i;
            int c4   = tid & 15;
            float4 v = *reinterpret_cast<const float4*>(&W[(size_t)(k0 + krow) * DOUT + c4 * 4]);
            *reinterpret_cast<float4*>(&wt[krow][c4 * 4]) = v;
        }
        __syncthreads();

        #pragma unroll
        for (int k = 0; k < 64; ++k) {
            float a[4], b[4];
            #pragma unroll
            for (int i = 0; i < 4; ++i) a[i] = xs[ty * 4 + i][k];
            #pragma unroll
            for (int j = 0; j < 4; ++j) b[j] = wt[k][tx * 4 + j];
            #pragma unroll
            for (int i = 0; i < 4; ++i)
                #pragma unroll
                for (int j = 0; j < 4; ++j)
                    acc[i][j] = fmaf(a[i], b[j], acc[i][j]);
        }
        __syncthreads();
    }

    #pragma unroll
    for (int i = 0; i < 4; ++i) {
        int grow = r0 + ty * 4 + i;
        if (grow >= n_nodes) continue;
        float ns = rsqrtf(fmaxf((float)outdeg[grow], 1.0f));
        float4 v = make_float4(acc[i][0] * ns, acc[i][1] * ns, acc[i][2] * ns, acc[i][3] * ns);
        *reinterpret_cast<float4*>(&h[(size_t)grow * DOUT + tx * 4]) = v;
    }
}

// ---------------- gather + finalize: one wave per dst node, lane = column ----------------
__global__ __launch_bounds__(256) void gather_kernel(
    const float* __restrict__ h, const int* __restrict__ rowptr,
    const int* __restrict__ col, const float* __restrict__ bias,
    float* __restrict__ out, int n_nodes)
{
    int wave = (blockIdx.x * blockDim.x + threadIdx.x) >> 6;
    int lane = threadIdx.x & 63;
    if (wave >= n_nodes) return;

    const int beg = rowptr[wave];
    const int end = rowptr[wave + 1];
    const int deg = end - beg;

    float acc = 0.f;
    int i = beg;
    for (; i + 4 <= end; i += 4) {
        int s0 = col[i], s1 = col[i + 1], s2 = col[i + 2], s3 = col[i + 3];
        float v0 = h[(size_t)s0 * DOUT + lane];
        float v1 = h[(size_t)s1 * DOUT + lane];
        float v2 = h[(size_t)s2 * DOUT + lane];
        float v3 = h[(size_t)s3 * DOUT + lane];
        acc += (v0 + v1) + (v2 + v3);
    }
    for (; i < end; ++i) {
        acc += h[(size_t)col[i] * DOUT + lane];
    }

    float nd = rsqrtf(fmaxf((float)deg, 1.0f));
    out[(size_t)wave * DOUT + lane] = fmaxf(fmaf(acc, nd, bias[lane]), 0.f);
}

extern "C" void kernel_launch(void* const* d_in, const int* in_sizes, int n_in,
                              void* d_out, int out_size, void* d_ws, size_t ws_size,
                              hipStream_t stream) {
    const float* x   = (const float*)d_in[0];
    const float* W   = (const float*)d_in[1];
    const float* b   = (const float*)d_in[2];
    const int*   src = (const int*)d_in[3];
    const int*   dst = (const int*)d_in[4];
    float* out = (float*)d_out;

    const int n_nodes = in_sizes[0] / DIN;   // 50000
    const int n_edges = in_sizes[3];         // 800000
    const int nsb = (n_nodes + SCAN_BLK - 1) / SCAN_BLK;  // scan blocks (196 <= 256)

    // workspace layout
    int* outdeg = (int*)d_ws;                  // n
    int* indeg  = outdeg + n_nodes;            // n
    int* rowptr = indeg + n_nodes;             // n+1
    int* cursor = rowptr + n_nodes + 1;        // n
    int* bsum   = cursor + n_nodes;            // nsb
    int* boff   = bsum + 256;                  // nsb (pad to 256)
    int* col    = boff + 256;                  // n_edges
    size_t int_count = (size_t)4 * n_nodes + 1 + 512 + n_edges;
    size_t h_off = ((int_count * sizeof(int) + 15) / 16) * 16;
    float* h = (float*)((char*)d_ws + h_off);  // n*64

    hipMemsetAsync(outdeg, 0, (size_t)2 * n_nodes * sizeof(int), stream);

    degree_kernel<<<(n_edges + 255) / 256, 256, 0, stream>>>(src, dst, outdeg, indeg, n_edges);
    partial_kernel<<<nsb, SCAN_BLK, 0, stream>>>(indeg, bsum, n_nodes);
    scan_bsums_kernel<<<1, 256, 0, stream>>>(bsum, boff, nsb);
    emit_kernel<<<nsb, SCAN_BLK, 0, stream>>>(indeg, boff, rowptr, cursor, n_nodes, n_edges);
    fill_csr_kernel<<<(n_edges + 255) / 256, 256, 0, stream>>>(src, dst, cursor, col, n_edges);
    gemm_norm_kernel<<<(n_nodes + 63) / 64, 256, 0, stream>>>(x, W, outdeg, h, n_nodes);
    gather_kernel<<<((size_t)n_nodes * 64 + 255) / 256, 256, 0, stream>>>(h, rowptr, col, b, out, n_nodes);
}